// Round 2
// baseline (1501.397 us; speedup 1.0000x reference)
//
#include <hip/hip_runtime.h>
#include <math.h>

// Problem constants
#define F_DIM 64
#define N_NODES 64
#define T_LEN 24
#define N_HEADS 8
#define BATCH 16
#define E_DIM 4096          // F_DIM * N_NODES
#define HD 512              // E / N_HEADS
#define QKV_N 12288         // 3*E
#define MB 384              // T_LEN * BATCH
#define TS 23               // T_LEN - 1
#define MP 368              // TS * BATCH

// ---------------------------------------------------------------------------
// Kernel 0: xt[t*16+b, f*64+n] = x[b, f, t, n]
// ---------------------------------------------------------------------------
__global__ void k_transpose(const float* __restrict__ x, float* __restrict__ xt) {
    int m = blockIdx.x;              // t*16 + b
    int t = m >> 4, b = m & 15;
    const float* xb = x + (size_t)b * (F_DIM * T_LEN * N_NODES) + (size_t)t * N_NODES;
    float* row = xt + (size_t)m * E_DIM;
    for (int e = threadIdx.x; e < E_DIM; e += 256) {
        int f = e >> 6, n = e & 63;
        row[e] = xb[(size_t)f * (T_LEN * N_NODES) + n];
    }
}

// ---------------------------------------------------------------------------
// Generic GEMM: C[M,N] = A[M,K] @ B[N,K]^T + bias[N]
// BM=BN=64, BK=32, 256 threads, 4x4 per-thread tile. fp32 (correctness round).
// ---------------------------------------------------------------------------
__global__ void k_gemm(const float* __restrict__ A, const float* __restrict__ B,
                       const float* __restrict__ bias, float* __restrict__ C,
                       int M, int N, int K) {
    constexpr int BM = 64, BN = 64, BK = 32;
    __shared__ float As[BK][BM + 4];   // k-major, padded
    __shared__ float Bs[BK][BN + 4];
    int tid = threadIdx.x;
    int n0 = blockIdx.x * BN;
    int m0 = blockIdx.y * BM;
    int ty = tid >> 4, tx = tid & 15;
    float acc[4][4] = {};
    for (int k0 = 0; k0 < K; k0 += BK) {
        #pragma unroll
        for (int i = 0; i < (BM * BK) / 256; ++i) {
            int e = tid + i * 256;
            int r = e >> 5, c = e & 31;
            int m = m0 + r;
            As[c][r] = (m < M) ? A[(size_t)m * K + k0 + c] : 0.f;
        }
        #pragma unroll
        for (int i = 0; i < (BN * BK) / 256; ++i) {
            int e = tid + i * 256;
            int r = e >> 5, c = e & 31;
            Bs[c][r] = B[(size_t)(n0 + r) * K + k0 + c];
        }
        __syncthreads();
        #pragma unroll
        for (int kk = 0; kk < BK; ++kk) {
            float4 av = *(const float4*)&As[kk][ty * 4];
            float4 bv = *(const float4*)&Bs[kk][tx * 4];
            float ar[4] = {av.x, av.y, av.z, av.w};
            float br[4] = {bv.x, bv.y, bv.z, bv.w};
            #pragma unroll
            for (int i = 0; i < 4; ++i)
                #pragma unroll
                for (int j = 0; j < 4; ++j)
                    acc[i][j] += ar[i] * br[j];
        }
        __syncthreads();
    }
    #pragma unroll
    for (int i = 0; i < 4; ++i) {
        int m = m0 + ty * 4 + i;
        if (m < M) {
            #pragma unroll
            for (int j = 0; j < 4; ++j) {
                int n = n0 + tx * 4 + j;
                C[(size_t)m * N + n] = acc[i][j] + bias[n];
            }
        }
    }
}

// ---------------------------------------------------------------------------
// Kernel 2: per (b,h): scores -> prefix softmax over keys -> query-averaged
// attention weights wbar[t, b, h, k] = (1/(t+1)) * sum_{q<=t} E[q,k]/S[q,t]
// ---------------------------------------------------------------------------
#define QPAD 516
__global__ void k_scores(const float* __restrict__ qkv, float* __restrict__ wbar) {
    int bh = blockIdx.x;             // b*8 + h
    int b = bh >> 3, h = bh & 7;
    __shared__ float qs[T_LEN * QPAD];   // ~49.5 KB
    __shared__ float ss[T_LEN][25];      // scores, then exp(base - rowmax)
    __shared__ float isv[T_LEN][25];     // 1 / prefix-sum
    int tid = threadIdx.x;
    for (int i = tid; i < T_LEN * HD; i += 256) {
        int t = i >> 9, d = i & 511;
        qs[t * QPAD + d] = qkv[(size_t)(t * BATCH + b) * QKV_N + h * HD + d];
    }
    __syncthreads();
    const float scale = 0.044194173824159216f;   // 1/sqrt(512)
    for (int p = tid; p < T_LEN * T_LEN; p += 256) {
        int qi = p / 24, ki = p % 24;
        const float* qp = &qs[qi * QPAD];
        const float* kp = qkv + (size_t)(ki * BATCH + b) * QKV_N + E_DIM + h * HD;
        float s = 0.f;
        #pragma unroll 4
        for (int d = 0; d < HD; d += 4) {
            float4 a = *(const float4*)&qp[d];
            float4 c = *(const float4*)&kp[d];
            s += a.x * c.x + a.y * c.y + a.z * c.z + a.w * c.w;
        }
        s *= scale;
        if (ki <= qi) s += 1.f;      // tril_add (includes diagonal)
        ss[qi][ki] = s;
    }
    __syncthreads();
    if (tid < T_LEN) {
        int q = tid;
        float M = -1e30f;
        for (int k = 0; k < T_LEN; ++k) M = fmaxf(M, ss[q][k]);
        float run = 0.f;
        for (int k = 0; k < T_LEN; ++k) {
            float e = __expf(ss[q][k] - M);
            ss[q][k] = e;
            run += e;
            isv[q][k] = 1.f / run;   // 1 / S[q, t=k]
        }
    }
    __syncthreads();
    for (int p = tid; p < TS * T_LEN; p += 256) {
        int t = p / 24, k = p % 24;
        float w = 0.f;
        if (k <= t) {
            float sum = 0.f;
            for (int q = 0; q <= t; ++q) sum += ss[q][k] * isv[q][t];
            w = sum / (float)(t + 1);
        }
        wbar[(size_t)((t * BATCH + b) * N_HEADS + h) * T_LEN + k] = w;
    }
}

// ---------------------------------------------------------------------------
// Kernel 3: cbar[t, b, h*512+d] = sum_k wbar[t,b,h,k] * v[k,b,h,d]
// ---------------------------------------------------------------------------
__global__ void k_cbar(const float* __restrict__ qkv, const float* __restrict__ wbar,
                       float* __restrict__ cbar) {
    int bh = blockIdx.x;
    int b = bh >> 3, h = bh & 7;
    __shared__ float vs[T_LEN * HD];   // 48 KB
    __shared__ float wb[TS * T_LEN];
    int tid = threadIdx.x;
    for (int i = tid; i < T_LEN * HD; i += 256) {
        int t = i >> 9, d = i & 511;
        vs[i] = qkv[(size_t)(t * BATCH + b) * QKV_N + 2 * E_DIM + h * HD + d];
    }
    for (int i = tid; i < TS * T_LEN; i += 256)
        wb[i] = wbar[(size_t)(((i / 24) * BATCH + b) * N_HEADS + h) * T_LEN + (i % 24)];
    __syncthreads();
    for (int t = 0; t < TS; ++t) {
        for (int d = tid; d < HD; d += 256) {
            float acc = 0.f;
            #pragma unroll
            for (int k = 0; k < T_LEN; ++k) acc += wb[t * 24 + k] * vs[k * HD + d];
            cbar[(size_t)(t * BATCH + b) * E_DIM + h * HD + d] = acc;
        }
    }
}

// ---------------------------------------------------------------------------
// Kernel 5: out[b, f, t+1, n] = relu( sum_g pooled[t,b, f*64+g] * Wfc[n,g] + bfc[n] )
// ---------------------------------------------------------------------------
__global__ void k_final(const float* __restrict__ pooled, const float* __restrict__ Wfc,
                        const float* __restrict__ bfc, float* __restrict__ out) {
    int tb = blockIdx.x;             // t*16 + b
    int t = tb >> 4, b = tb & 15;
    __shared__ float ps[E_DIM];      // 16 KB
    __shared__ float wf[64 * 65];    // padded
    __shared__ float bf[64];
    int tid = threadIdx.x;
    for (int i = tid; i < E_DIM; i += 256) ps[i] = pooled[(size_t)tb * E_DIM + i];
    for (int i = tid; i < 64 * 64; i += 256) wf[(i >> 6) * 65 + (i & 63)] = Wfc[i];
    if (tid < 64) bf[tid] = bfc[tid];
    __syncthreads();
    for (int p = tid; p < 4096; p += 256) {
        int f = p >> 6, n = p & 63;
        float acc = bf[n];
        #pragma unroll
        for (int g = 0; g < 64; ++g) acc += ps[f * 64 + g] * wf[n * 65 + g];
        out[(size_t)((b * 64 + f) * T_LEN + (t + 1)) * N_NODES + n] = fmaxf(acc, 0.f);
    }
}

// Kernel 6: copy first frame (t=0): out[b,f,0,n] = x[b,f,0,n]
// 65536 elements total -> 256 blocks x 256 threads. (R0 bug: grid was 16x too
// large, wrote ~100MB past d_out -> HSA abort.)
__global__ void k_first(const float* __restrict__ x, float* __restrict__ out) {
    int idx = blockIdx.x * 256 + threadIdx.x;
    if (idx >= BATCH * F_DIM * N_NODES) return;
    int b = idx >> 12, f = (idx >> 6) & 63, n = idx & 63;
    size_t o = ((size_t)(b * 64 + f) * T_LEN) * 64 + n;
    out[o] = x[o];
}

extern "C" void kernel_launch(void* const* d_in, const int* in_sizes, int n_in,
                              void* d_out, int out_size, void* d_ws, size_t ws_size,
                              hipStream_t stream) {
    const float* x    = (const float*)d_in[0];
    const float* Wqkv = (const float*)d_in[1];
    const float* bqkv = (const float*)d_in[2];
    const float* Wo   = (const float*)d_in[3];
    const float* bo   = (const float*)d_in[4];
    const float* Wfc  = (const float*)d_in[5];
    const float* bfc  = (const float*)d_in[6];
    float* out = (float*)d_out;

    // workspace layout (floats): xt | qkv | wbar | cbar | pooled  (~37.5 MB)
    float* ws     = (float*)d_ws;
    float* xt     = ws;
    float* qkv    = xt   + (size_t)MB * E_DIM;
    float* wbar   = qkv  + (size_t)MB * QKV_N;
    float* cbar   = wbar + (size_t)TS * BATCH * N_HEADS * T_LEN;
    float* pooled = cbar + (size_t)MP * E_DIM;

    hipLaunchKernelGGL(k_transpose, dim3(MB), dim3(256), 0, stream, x, xt);
    hipLaunchKernelGGL(k_gemm, dim3(QKV_N / 64, MB / 64), dim3(256), 0, stream,
                       xt, Wqkv, bqkv, qkv, MB, QKV_N, E_DIM);
    hipLaunchKernelGGL(k_scores, dim3(BATCH * N_HEADS), dim3(256), 0, stream, qkv, wbar);
    hipLaunchKernelGGL(k_cbar, dim3(BATCH * N_HEADS), dim3(256), 0, stream, qkv, wbar, cbar);
    hipLaunchKernelGGL(k_gemm, dim3(E_DIM / 64, (MP + 63) / 64), dim3(256), 0, stream,
                       cbar, Wo, bo, pooled, MP, E_DIM, E_DIM);
    hipLaunchKernelGGL(k_final, dim3(TS * BATCH), dim3(256), 0, stream, pooled, Wfc, bfc, out);
    hipLaunchKernelGGL(k_first, dim3((BATCH * F_DIM * N_NODES + 255) / 256), dim3(256), 0, stream, x, out);
}

// Round 3
// 706.820 us; speedup vs baseline: 2.1242x; 2.1242x over previous
//
#include <hip/hip_runtime.h>
#include <math.h>

// Problem constants
#define F_DIM 64
#define N_NODES 64
#define T_LEN 24
#define N_HEADS 8
#define BATCH 16
#define E_DIM 4096          // F_DIM * N_NODES
#define HD 512              // E / N_HEADS
#define QKV_N 12288         // 3*E
#define MB 384              // T_LEN * BATCH
#define TS 23               // T_LEN - 1
#define MP 368              // TS * BATCH

typedef unsigned short ushort_t;
typedef short bf16x8 __attribute__((ext_vector_type(8)));
typedef float f32x4 __attribute__((ext_vector_type(4)));

// fp32 -> bf16, round-half-up (add 0x8000, truncate)
__device__ inline ushort_t f2bf(float f) {
    return (ushort_t)((__float_as_uint(f) + 0x8000u) >> 16);
}

// async global->LDS, 16B per lane. LDS dest = uniform base + lane*16.
__device__ inline void async_load16(const ushort_t* g, ushort_t* lds) {
    __builtin_amdgcn_global_load_lds(
        (const __attribute__((address_space(1))) unsigned int*)g,
        (__attribute__((address_space(3))) unsigned int*)lds,
        16, 0, 0);
}

// ---------------------------------------------------------------------------
// Kernel 0: xt[t*16+b, f*64+n] = bf16(x[b, f, t, n])
// ---------------------------------------------------------------------------
__global__ void k_transpose(const float* __restrict__ x, ushort_t* __restrict__ xt) {
    int m = blockIdx.x;              // t*16 + b
    int t = m >> 4, b = m & 15;
    const float* xb = x + (size_t)b * (F_DIM * T_LEN * N_NODES) + (size_t)t * N_NODES;
    ushort_t* row = xt + (size_t)m * E_DIM;
    for (int e = threadIdx.x; e < E_DIM; e += 256) {
        int f = e >> 6, n = e & 63;
        row[e] = f2bf(xb[(size_t)f * (T_LEN * N_NODES) + n]);
    }
}

// ---------------------------------------------------------------------------
// MFMA GEMM: C[M,N] = bf16(A)[M,K] @ bf16(B[N,K])^T + bias[N]
// A: bf16 in ws (rows padded to 384). B: fp32 weights, converted during
// LDS staging via v_perm. 128x128 tile, BK=32, 4 waves x (4x4 16x16x32 frags).
// ---------------------------------------------------------------------------
__global__ __launch_bounds__(256) void k_gemm_mfma(
    const ushort_t* __restrict__ A, const float* __restrict__ B,
    const float* __restrict__ bias, float* __restrict__ C,
    int M, int N, int K)
{
    __shared__ __align__(16) ushort_t As[128 * 32];   // 8 KB
    __shared__ __align__(16) ushort_t Bs[128 * 32];   // 8 KB
    const int tid  = threadIdx.x;
    const int wave = tid >> 6, lane = tid & 63;
    const int wm = wave >> 1, wn = wave & 1;
    const int lr = lane & 15, lq = lane >> 4;
    const int n0 = blockIdx.x * 128, m0 = blockIdx.y * 128;

    f32x4 acc[4][4];
    #pragma unroll
    for (int i = 0; i < 4; ++i)
        #pragma unroll
        for (int j = 0; j < 4; ++j)
            acc[i][j] = (f32x4){0.f, 0.f, 0.f, 0.f};

    // A-staging geometry (byte index within 8192-B tile; identity LDS map)
    const int jA0 = ((wave * 2 + 0) * 64 + lane) * 16;
    const int jA1 = ((wave * 2 + 1) * 64 + lane) * 16;
    const int rA0 = jA0 >> 6, kA0 = (jA0 & 63) >> 1;   // row, ushort offset
    const int rA1 = jA1 >> 6, kA1 = (jA1 & 63) >> 1;
    const ushort_t* gA0 = A + (size_t)(m0 + rA0) * K + kA0;
    const ushort_t* gA1 = A + (size_t)(m0 + rA1) * K + kA1;
    ushort_t* lA0 = As + (wave * 2 + 0) * 512;   // 1024 B = 512 ushorts
    ushort_t* lA1 = As + (wave * 2 + 1) * 512;

    for (int k0 = 0; k0 < K; k0 += 32) {
        // --- stage A (async, bf16 already) ---
        async_load16(gA0 + k0, lA0);
        async_load16(gA1 + k0, lA1);
        // --- stage B (fp32 -> bf16 via v_perm, coalesced 1KB/inst loads) ---
        #pragma unroll
        for (int s = 0; s < 4; ++s) {
            int e4  = tid + s * 256;       // float4 index in 128x32 tile
            int row = e4 >> 3;
            int kq  = (e4 & 7) * 4;
            const float4 v = *(const float4*)(B + (size_t)(n0 + row) * K + k0 + kq);
            unsigned int ux = __float_as_uint(v.x) + 0x8000u;
            unsigned int uy = __float_as_uint(v.y) + 0x8000u;
            unsigned int uz = __float_as_uint(v.z) + 0x8000u;
            unsigned int uw = __float_as_uint(v.w) + 0x8000u;
            unsigned int p0 = __builtin_amdgcn_perm(uy, ux, 0x07060302u);
            unsigned int p1 = __builtin_amdgcn_perm(uw, uz, 0x07060302u);
            *(uint2*)&Bs[row * 32 + kq] = make_uint2(p0, p1);
        }
        __syncthreads();
        // --- fragments + MFMA ---
        bf16x8 af[4], bfr[4];
        #pragma unroll
        for (int i = 0; i < 4; ++i)
            af[i] = *(const bf16x8*)&As[(wm * 64 + i * 16 + lr) * 32 + lq * 8];
        #pragma unroll
        for (int j = 0; j < 4; ++j)
            bfr[j] = *(const bf16x8*)&Bs[(wn * 64 + j * 16 + lr) * 32 + lq * 8];
        #pragma unroll
        for (int i = 0; i < 4; ++i)
            #pragma unroll
            for (int j = 0; j < 4; ++j)
                acc[i][j] = __builtin_amdgcn_mfma_f32_16x16x32_bf16(af[i], bfr[j], acc[i][j], 0, 0, 0);
        __syncthreads();
    }

    // --- epilogue: C = acc + bias, row-guarded ---
    float bj[4];
    #pragma unroll
    for (int j = 0; j < 4; ++j)
        bj[j] = bias[n0 + wn * 64 + j * 16 + lr];
    #pragma unroll
    for (int i = 0; i < 4; ++i) {
        int mi = m0 + wm * 64 + i * 16 + lq * 4;
        #pragma unroll
        for (int r = 0; r < 4; ++r) {
            int m = mi + r;
            if (m < M) {
                #pragma unroll
                for (int j = 0; j < 4; ++j) {
                    int n = n0 + wn * 64 + j * 16 + lr;
                    C[(size_t)m * N + n] = acc[i][j][r] + bj[j];
                }
            }
        }
    }
}

// ---------------------------------------------------------------------------
// k_scores: per (b,h): wave-per-dot QK^T (coalesced), prefix softmax,
// wbar[t,b,h,k] = (1/(t+1)) * sum_{q<=t} E[q,k]/S[q,t]
// ---------------------------------------------------------------------------
__global__ void k_scores(const float* __restrict__ qkv, float* __restrict__ wbar) {
    int bh = blockIdx.x;             // b*8 + h
    int b = bh >> 3, h = bh & 7;
    __shared__ float ss[T_LEN][25];
    __shared__ float isv[T_LEN][25];
    int tid = threadIdx.x, wave = tid >> 6, lane = tid & 63;
    const float scale = 0.044194173824159216f;   // 1/sqrt(512)
    for (int p = wave; p < T_LEN * T_LEN; p += 8) {   // 512 thr = 8 waves
        int qi = p / 24, ki = p - qi * 24;
        const float* qp = qkv + (size_t)(qi * BATCH + b) * QKV_N + h * HD + lane * 8;
        const float* kp = qkv + (size_t)(ki * BATCH + b) * QKV_N + E_DIM + h * HD + lane * 8;
        float4 a0 = *(const float4*)qp, a1 = *(const float4*)(qp + 4);
        float4 c0 = *(const float4*)kp, c1 = *(const float4*)(kp + 4);
        float s = a0.x * c0.x + a0.y * c0.y + a0.z * c0.z + a0.w * c0.w
                + a1.x * c1.x + a1.y * c1.y + a1.z * c1.z + a1.w * c1.w;
        #pragma unroll
        for (int off = 32; off > 0; off >>= 1) s += __shfl_xor(s, off);
        if (lane == 0) {
            s *= scale;
            if (ki <= qi) s += 1.f;      // tril_add (includes diagonal)
            ss[qi][ki] = s;
        }
    }
    __syncthreads();
    if (tid < T_LEN) {
        int q = tid;
        float M = -1e30f;
        for (int k = 0; k < T_LEN; ++k) M = fmaxf(M, ss[q][k]);
        float run = 0.f;
        for (int k = 0; k < T_LEN; ++k) {
            float e = __expf(ss[q][k] - M);
            ss[q][k] = e;
            run += e;
            isv[q][k] = 1.f / run;   // 1 / S[q, t=k]
        }
    }
    __syncthreads();
    for (int p = tid; p < TS * T_LEN; p += 512) {
        int t = p / 24, k = p - t * 24;
        float w = 0.f;
        if (k <= t) {
            float sum = 0.f;
            for (int q = 0; q <= t; ++q) sum += ss[q][k] * isv[q][t];
            w = sum / (float)(t + 1);
        }
        wbar[(size_t)((t * BATCH + b) * N_HEADS + h) * T_LEN + k] = w;
    }
}

// ---------------------------------------------------------------------------
// k_cbar: cbar[t*16+b, h*512+d] = bf16( sum_k wbar[t,b,h,k] * v[k,b,h,d] )
// ---------------------------------------------------------------------------
__global__ void k_cbar(const float* __restrict__ qkv, const float* __restrict__ wbar,
                       ushort_t* __restrict__ cbar) {
    int bh = blockIdx.x;
    int b = bh >> 3, h = bh & 7;
    __shared__ float vs[T_LEN * HD];   // 48 KB
    __shared__ float wb[TS * T_LEN];
    int tid = threadIdx.x;
    for (int i4 = tid; i4 < T_LEN * HD / 4; i4 += 256) {
        int t = i4 >> 7, d4 = i4 & 127;
        *(float4*)&vs[t * HD + d4 * 4] =
            *(const float4*)&qkv[(size_t)(t * BATCH + b) * QKV_N + 2 * E_DIM + h * HD + d4 * 4];
    }
    for (int i = tid; i < TS * T_LEN; i += 256)
        wb[i] = wbar[(size_t)(((i / 24) * BATCH + b) * N_HEADS + h) * T_LEN + (i % 24)];
    __syncthreads();
    for (int t = 0; t < TS; ++t) {
        for (int d = tid; d < HD; d += 256) {
            float acc = 0.f;
            #pragma unroll
            for (int k = 0; k < T_LEN; ++k) acc += wb[t * 24 + k] * vs[k * HD + d];
            cbar[(size_t)(t * BATCH + b) * E_DIM + h * HD + d] = f2bf(acc);
        }
    }
}

// ---------------------------------------------------------------------------
// k_final: out[b, f, t+1, n] = relu( sum_g pooled[t*16+b, f*64+g]*Wfc[n,g] + bfc[n] )
// ---------------------------------------------------------------------------
__global__ void k_final(const float* __restrict__ pooled, const float* __restrict__ Wfc,
                        const float* __restrict__ bfc, float* __restrict__ out) {
    int tb = blockIdx.x;             // t*16 + b
    int t = tb >> 4, b = tb & 15;
    __shared__ float ps[E_DIM];      // 16 KB
    __shared__ float wf[64 * 65];    // padded
    __shared__ float bf[64];
    int tid = threadIdx.x;
    for (int i = tid; i < E_DIM; i += 256) ps[i] = pooled[(size_t)tb * E_DIM + i];
    for (int i = tid; i < 64 * 64; i += 256) wf[(i >> 6) * 65 + (i & 63)] = Wfc[i];
    if (tid < 64) bf[tid] = bfc[tid];
    __syncthreads();
    for (int p = tid; p < 4096; p += 256) {
        int f = p >> 6, n = p & 63;
        float acc = bf[n];
        #pragma unroll
        for (int g = 0; g < 64; ++g) acc += ps[f * 64 + g] * wf[n * 65 + g];
        out[(size_t)((b * 64 + f) * T_LEN + (t + 1)) * N_NODES + n] = fmaxf(acc, 0.f);
    }
}

// k_first: out[b,f,0,n] = x[b,f,0,n]   (65536 elems, 256 blocks)
__global__ void k_first(const float* __restrict__ x, float* __restrict__ out) {
    int idx = blockIdx.x * 256 + threadIdx.x;
    if (idx >= BATCH * F_DIM * N_NODES) return;
    int b = idx >> 12, f = (idx >> 6) & 63, n = idx & 63;
    size_t o = ((size_t)(b * 64 + f) * T_LEN) * 64 + n;
    out[o] = x[o];
}

extern "C" void kernel_launch(void* const* d_in, const int* in_sizes, int n_in,
                              void* d_out, int out_size, void* d_ws, size_t ws_size,
                              hipStream_t stream) {
    const float* x    = (const float*)d_in[0];
    const float* Wqkv = (const float*)d_in[1];
    const float* bqkv = (const float*)d_in[2];
    const float* Wo   = (const float*)d_in[3];
    const float* bo   = (const float*)d_in[4];
    const float* Wfc  = (const float*)d_in[5];
    const float* bfc  = (const float*)d_in[6];
    float* out = (float*)d_out;

    // ws layout (bytes): xt bf16 | qkv f32 | wbar f32 | cbar bf16(384 rows) | pooled f32
    char* wsb = (char*)d_ws;
    ushort_t* xt   = (ushort_t*)wsb;                                   // 3,145,728
    float*    qkv  = (float*)(wsb + 3145728);                          // 18,874,368
    float*    wbar = (float*)(wsb + 3145728 + 18874368);               //   282,624
    ushort_t* cbar = (ushort_t*)(wsb + 3145728 + 18874368 + 282624);   // 3,145,728
    float*  pooled = (float*)(wsb + 3145728 + 18874368 + 282624 + 3145728);

    hipLaunchKernelGGL(k_transpose, dim3(MB), dim3(256), 0, stream, x, xt);
    hipLaunchKernelGGL(k_gemm_mfma, dim3(QKV_N / 128, 3), dim3(256), 0, stream,
                       xt, Wqkv, bqkv, qkv, MB, QKV_N, E_DIM);
    hipLaunchKernelGGL(k_scores, dim3(BATCH * N_HEADS), dim3(512), 0, stream, qkv, wbar);
    hipLaunchKernelGGL(k_cbar, dim3(BATCH * N_HEADS), dim3(256), 0, stream, qkv, wbar, cbar);
    hipLaunchKernelGGL(k_gemm_mfma, dim3(E_DIM / 128, 3), dim3(256), 0, stream,
                       cbar, Wo, bo, pooled, MP, E_DIM, E_DIM);
    hipLaunchKernelGGL(k_final, dim3(TS * BATCH), dim3(256), 0, stream, pooled, Wfc, bfc, out);
    hipLaunchKernelGGL(k_first, dim3((BATCH * F_DIM * N_NODES + 255) / 256), dim3(256), 0, stream, x, out);
}

// Round 4
// 559.487 us; speedup vs baseline: 2.6835x; 1.2633x over previous
//
#include <hip/hip_runtime.h>
#include <math.h>

// Problem constants
#define F_DIM 64
#define N_NODES 64
#define T_LEN 24
#define N_HEADS 8
#define BATCH 16
#define E_DIM 4096          // F_DIM * N_NODES
#define HD 512              // E / N_HEADS
#define QKV_N 12288         // 3*E
#define MB 384              // T_LEN * BATCH
#define TS 23               // T_LEN - 1
#define MP 368              // TS * BATCH
#define MPAD 384            // padded row count for both GEMMs

typedef unsigned short ushort_t;
typedef short bf16x8 __attribute__((ext_vector_type(8)));
typedef float f32x4 __attribute__((ext_vector_type(4)));

// fp32 -> bf16, round-half-up (add 0x8000, truncate)
__device__ inline ushort_t f2bf(float f) {
    return (ushort_t)((__float_as_uint(f) + 0x8000u) >> 16);
}

// async global->LDS, 16B per lane. LDS dest = uniform base + lane*16.
__device__ inline void async_load16(const ushort_t* g, ushort_t* lds) {
    __builtin_amdgcn_global_load_lds(
        (const __attribute__((address_space(1))) unsigned int*)g,
        (__attribute__((address_space(3))) unsigned int*)lds,
        16, 0, 0);
}

// ---------------------------------------------------------------------------
// Kernel 0: xt[t*16+b, f*64+n] = bf16(x[b, f, t, n])
// ---------------------------------------------------------------------------
__global__ void k_transpose(const float* __restrict__ x, ushort_t* __restrict__ xt) {
    int m = blockIdx.x;              // t*16 + b
    int t = m >> 4, b = m & 15;
    const float* xb = x + (size_t)b * (F_DIM * T_LEN * N_NODES) + (size_t)t * N_NODES;
    ushort_t* row = xt + (size_t)m * E_DIM;
    for (int e = threadIdx.x; e < E_DIM; e += 256) {
        int f = e >> 6, n = e & 63;
        row[e] = f2bf(xb[(size_t)f * (T_LEN * N_NODES) + n]);
    }
}

// ---------------------------------------------------------------------------
// MFMA GEMM with K-split: P[z, 0:384, n-tile] = bf16(A)[:, kz:kz+kc] @ bf16(B)^T
// A: bf16 in ws, rows padded to 384. B: fp32 weights, converted during LDS
// staging via v_perm. 128x128 tile, BK=32, 4 waves x (4x4 16x16x32 frags).
// blockIdx.z = K-chunk (kc columns each). Raw partials, bias added in reduce.
// ---------------------------------------------------------------------------
__global__ __launch_bounds__(256) void k_gemm_mfma(
    const ushort_t* __restrict__ A, const float* __restrict__ B,
    float* __restrict__ P, int N, int K, int kc)
{
    __shared__ __align__(16) ushort_t As[128 * 32];   // 8 KB
    __shared__ __align__(16) ushort_t Bs[128 * 32];   // 8 KB
    const int tid  = threadIdx.x;
    const int wave = tid >> 6, lane = tid & 63;
    const int wm = wave >> 1, wn = wave & 1;
    const int lr = lane & 15, lq = lane >> 4;
    const int n0 = blockIdx.x * 128, m0 = blockIdx.y * 128;
    const int kz = blockIdx.z * kc;

    f32x4 acc[4][4];
    #pragma unroll
    for (int i = 0; i < 4; ++i)
        #pragma unroll
        for (int j = 0; j < 4; ++j)
            acc[i][j] = (f32x4){0.f, 0.f, 0.f, 0.f};

    // A-staging geometry (byte index within 8192-B tile; identity LDS map)
    const int jA0 = ((wave * 2 + 0) * 64 + lane) * 16;
    const int jA1 = ((wave * 2 + 1) * 64 + lane) * 16;
    const int rA0 = jA0 >> 6, kA0 = (jA0 & 63) >> 1;   // row, ushort offset
    const int rA1 = jA1 >> 6, kA1 = (jA1 & 63) >> 1;
    const ushort_t* gA0 = A + (size_t)(m0 + rA0) * K + kA0;
    const ushort_t* gA1 = A + (size_t)(m0 + rA1) * K + kA1;
    ushort_t* lA0 = As + (wave * 2 + 0) * 512;   // 1024 B = 512 ushorts
    ushort_t* lA1 = As + (wave * 2 + 1) * 512;

    for (int k0 = kz; k0 < kz + kc; k0 += 32) {
        // --- stage A (async, bf16 already) ---
        async_load16(gA0 + k0, lA0);
        async_load16(gA1 + k0, lA1);
        // --- stage B (fp32 -> bf16 via v_perm, coalesced 1KB/inst loads) ---
        #pragma unroll
        for (int s = 0; s < 4; ++s) {
            int e4  = tid + s * 256;       // float4 index in 128x32 tile
            int row = e4 >> 3;
            int kq  = (e4 & 7) * 4;
            const float4 v = *(const float4*)(B + (size_t)(n0 + row) * K + k0 + kq);
            unsigned int ux = __float_as_uint(v.x) + 0x8000u;
            unsigned int uy = __float_as_uint(v.y) + 0x8000u;
            unsigned int uz = __float_as_uint(v.z) + 0x8000u;
            unsigned int uw = __float_as_uint(v.w) + 0x8000u;
            unsigned int p0 = __builtin_amdgcn_perm(uy, ux, 0x07060302u);
            unsigned int p1 = __builtin_amdgcn_perm(uw, uz, 0x07060302u);
            *(uint2*)&Bs[row * 32 + kq] = make_uint2(p0, p1);
        }
        __syncthreads();
        // --- fragments + MFMA ---
        bf16x8 af[4], bfr[4];
        #pragma unroll
        for (int i = 0; i < 4; ++i)
            af[i] = *(const bf16x8*)&As[(wm * 64 + i * 16 + lr) * 32 + lq * 8];
        #pragma unroll
        for (int j = 0; j < 4; ++j)
            bfr[j] = *(const bf16x8*)&Bs[(wn * 64 + j * 16 + lr) * 32 + lq * 8];
        #pragma unroll
        for (int i = 0; i < 4; ++i)
            #pragma unroll
            for (int j = 0; j < 4; ++j)
                acc[i][j] = __builtin_amdgcn_mfma_f32_16x16x32_bf16(af[i], bfr[j], acc[i][j], 0, 0, 0);
        __syncthreads();
    }

    // --- epilogue: raw partial store (no bias, no guard; M padded to 384) ---
    float* Pz = P + (size_t)blockIdx.z * MPAD * N;
    #pragma unroll
    for (int i = 0; i < 4; ++i) {
        int mi = m0 + wm * 64 + i * 16 + lq * 4;
        #pragma unroll
        for (int r = 0; r < 4; ++r) {
            #pragma unroll
            for (int j = 0; j < 4; ++j) {
                int n = n0 + wn * 64 + j * 16 + lr;
                Pz[(size_t)(mi + r) * N + n] = acc[i][j][r];
            }
        }
    }
}

// ---------------------------------------------------------------------------
// k_reduce: C[m,n] = sum_s P[s,m,n] + bias[n]   (float4-vectorized)
// ---------------------------------------------------------------------------
__global__ void k_reduce(const float* __restrict__ P, const float* __restrict__ bias,
                         float* __restrict__ C, int N, int S) {
    int idx = blockIdx.x * 256 + threadIdx.x;      // float4 index
    size_t e = (size_t)idx * 4;                    // grid sized exactly
    int n = (int)(e % N);
    float4 a = *(const float4*)(P + e);
    for (int s = 1; s < S; ++s) {
        const float4 b = *(const float4*)(P + (size_t)s * MPAD * N + e);
        a.x += b.x; a.y += b.y; a.z += b.z; a.w += b.w;
    }
    const float4 bb = *(const float4*)(bias + n);
    a.x += bb.x; a.y += bb.y; a.z += bb.z; a.w += bb.w;
    *(float4*)(C + e) = a;
}

// ---------------------------------------------------------------------------
// k_scores: per (b,h): wave-per-dot QK^T (coalesced), prefix softmax,
// wbar[t,b,h,k] = (1/(t+1)) * sum_{q<=t} E[q,k]/S[q,t]
// ---------------------------------------------------------------------------
__global__ void k_scores(const float* __restrict__ qkv, float* __restrict__ wbar) {
    int bh = blockIdx.x;             // b*8 + h
    int b = bh >> 3, h = bh & 7;
    __shared__ float ss[T_LEN][25];
    __shared__ float isv[T_LEN][25];
    int tid = threadIdx.x, wave = tid >> 6, lane = tid & 63;
    const float scale = 0.044194173824159216f;   // 1/sqrt(512)
    for (int p = wave; p < T_LEN * T_LEN; p += 8) {   // 512 thr = 8 waves
        int qi = p / 24, ki = p - qi * 24;
        const float* qp = qkv + (size_t)(qi * BATCH + b) * QKV_N + h * HD + lane * 8;
        const float* kp = qkv + (size_t)(ki * BATCH + b) * QKV_N + E_DIM + h * HD + lane * 8;
        float4 a0 = *(const float4*)qp, a1 = *(const float4*)(qp + 4);
        float4 c0 = *(const float4*)kp, c1 = *(const float4*)(kp + 4);
        float s = a0.x * c0.x + a0.y * c0.y + a0.z * c0.z + a0.w * c0.w
                + a1.x * c1.x + a1.y * c1.y + a1.z * c1.z + a1.w * c1.w;
        #pragma unroll
        for (int off = 32; off > 0; off >>= 1) s += __shfl_xor(s, off);
        if (lane == 0) {
            s *= scale;
            if (ki <= qi) s += 1.f;      // tril_add (includes diagonal)
            ss[qi][ki] = s;
        }
    }
    __syncthreads();
    if (tid < T_LEN) {
        int q = tid;
        float M = -1e30f;
        for (int k = 0; k < T_LEN; ++k) M = fmaxf(M, ss[q][k]);
        float run = 0.f;
        for (int k = 0; k < T_LEN; ++k) {
            float e = __expf(ss[q][k] - M);
            ss[q][k] = e;
            run += e;
            isv[q][k] = 1.f / run;   // 1 / S[q, t=k]
        }
    }
    __syncthreads();
    for (int p = tid; p < TS * T_LEN; p += 512) {
        int t = p / 24, k = p - t * 24;
        float w = 0.f;
        if (k <= t) {
            float sum = 0.f;
            for (int q = 0; q <= t; ++q) sum += ss[q][k] * isv[q][t];
            w = sum / (float)(t + 1);
        }
        wbar[(size_t)((t * BATCH + b) * N_HEADS + h) * T_LEN + k] = w;
    }
}

// ---------------------------------------------------------------------------
// k_cbar: cbar[t*16+b, h*512+d] = bf16( sum_k wbar[t,b,h,k] * v[k,b,h,d] )
// ---------------------------------------------------------------------------
__global__ void k_cbar(const float* __restrict__ qkv, const float* __restrict__ wbar,
                       ushort_t* __restrict__ cbar) {
    int bh = blockIdx.x;
    int b = bh >> 3, h = bh & 7;
    __shared__ float vs[T_LEN * HD];   // 48 KB
    __shared__ float wb[TS * T_LEN];
    int tid = threadIdx.x;
    for (int i4 = tid; i4 < T_LEN * HD / 4; i4 += 256) {
        int t = i4 >> 7, d4 = i4 & 127;
        *(float4*)&vs[t * HD + d4 * 4] =
            *(const float4*)&qkv[(size_t)(t * BATCH + b) * QKV_N + 2 * E_DIM + h * HD + d4 * 4];
    }
    for (int i = tid; i < TS * T_LEN; i += 256)
        wb[i] = wbar[(size_t)(((i / 24) * BATCH + b) * N_HEADS + h) * T_LEN + (i % 24)];
    __syncthreads();
    for (int t = 0; t < TS; ++t) {
        for (int d = tid; d < HD; d += 256) {
            float acc = 0.f;
            #pragma unroll
            for (int k = 0; k < T_LEN; ++k) acc += wb[t * 24 + k] * vs[k * HD + d];
            cbar[(size_t)(t * BATCH + b) * E_DIM + h * HD + d] = f2bf(acc);
        }
    }
}

// ---------------------------------------------------------------------------
// k_final: out[b, f, t+1, n] = relu( sum_g pooled[t*16+b, f*64+g]*Wfc[n,g] + bfc[n] )
// ---------------------------------------------------------------------------
__global__ void k_final(const float* __restrict__ pooled, const float* __restrict__ Wfc,
                        const float* __restrict__ bfc, float* __restrict__ out) {
    int tb = blockIdx.x;             // t*16 + b
    int t = tb >> 4, b = tb & 15;
    __shared__ float ps[E_DIM];      // 16 KB
    __shared__ float wf[64 * 65];    // padded
    __shared__ float bf[64];
    int tid = threadIdx.x;
    for (int i = tid; i < E_DIM; i += 256) ps[i] = pooled[(size_t)tb * E_DIM + i];
    for (int i = tid; i < 64 * 64; i += 256) wf[(i >> 6) * 65 + (i & 63)] = Wfc[i];
    if (tid < 64) bf[tid] = bfc[tid];
    __syncthreads();
    for (int p = tid; p < 4096; p += 256) {
        int f = p >> 6, n = p & 63;
        float acc = bf[n];
        #pragma unroll
        for (int g = 0; g < 64; ++g) acc += ps[f * 64 + g] * wf[n * 65 + g];
        out[(size_t)((b * 64 + f) * T_LEN + (t + 1)) * N_NODES + n] = fmaxf(acc, 0.f);
    }
}

// k_first: out[b,f,0,n] = x[b,f,0,n]   (65536 elems, 256 blocks)
__global__ void k_first(const float* __restrict__ x, float* __restrict__ out) {
    int idx = blockIdx.x * 256 + threadIdx.x;
    if (idx >= BATCH * F_DIM * N_NODES) return;
    int b = idx >> 12, f = (idx >> 6) & 63, n = idx & 63;
    size_t o = ((size_t)(b * 64 + f) * T_LEN) * 64 + n;
    out[o] = x[o];
}

extern "C" void kernel_launch(void* const* d_in, const int* in_sizes, int n_in,
                              void* d_out, int out_size, void* d_ws, size_t ws_size,
                              hipStream_t stream) {
    const float* x    = (const float*)d_in[0];
    const float* Wqkv = (const float*)d_in[1];
    const float* bqkv = (const float*)d_in[2];
    const float* Wo   = (const float*)d_in[3];
    const float* bo   = (const float*)d_in[4];
    const float* Wfc  = (const float*)d_in[5];
    const float* bfc  = (const float*)d_in[6];
    float* out = (float*)d_out;

    // ws layout (bytes):
    //   xt bf16 (384x4096)      3,145,728
    //   qkv f32 (384x12288)    18,874,368
    //   wbar f32                  282,624
    //   cbar bf16 (384x4096)    3,145,728
    //   pooled f32 (384x4096)   6,291,456
    //   pbuf f32 (S x 384x12288) partials
    char* wsb = (char*)d_ws;
    ushort_t* xt   = (ushort_t*)wsb;
    float*    qkv  = (float*)(wsb + 3145728);
    float*    wbar = (float*)(wsb + 3145728 + 18874368);
    ushort_t* cbar = (ushort_t*)(wsb + 3145728 + 18874368 + 282624);
    float*  pooled = (float*)(wsb + 3145728 + 18874368 + 282624 + 3145728);
    size_t base    = 3145728 + 18874368 + 282624 + 3145728 + 6291456;
    float*  pbuf   = (float*)(wsb + base);

    const size_t pstride = (size_t)MPAD * QKV_N * 4;   // one QKV partial: 18.87 MB
    int S = 1;
    if (ws_size >= base + 4 * pstride) S = 4;
    else if (ws_size >= base + 2 * pstride) S = 2;
    int Swo = 2 * S;                                   // Wo partials are 3x smaller

    hipLaunchKernelGGL(k_transpose, dim3(MB), dim3(256), 0, stream, x, xt);

    hipLaunchKernelGGL(k_gemm_mfma, dim3(QKV_N / 128, 3, S), dim3(256), 0, stream,
                       xt, Wqkv, pbuf, QKV_N, E_DIM, E_DIM / S);
    hipLaunchKernelGGL(k_reduce, dim3(MPAD * QKV_N / 4 / 256), dim3(256), 0, stream,
                       pbuf, bqkv, qkv, QKV_N, S);

    hipLaunchKernelGGL(k_scores, dim3(BATCH * N_HEADS), dim3(512), 0, stream, qkv, wbar);
    hipLaunchKernelGGL(k_cbar, dim3(BATCH * N_HEADS), dim3(256), 0, stream, qkv, wbar, cbar);

    hipLaunchKernelGGL(k_gemm_mfma, dim3(E_DIM / 128, 3, Swo), dim3(256), 0, stream,
                       cbar, Wo, pbuf, E_DIM, E_DIM, E_DIM / Swo);
    hipLaunchKernelGGL(k_reduce, dim3(MPAD * E_DIM / 4 / 256), dim3(256), 0, stream,
                       pbuf, bo, pooled, E_DIM, Swo);

    hipLaunchKernelGGL(k_final, dim3(TS * BATCH), dim3(256), 0, stream, pooled, Wfc, bfc, out);
    hipLaunchKernelGGL(k_first, dim3((BATCH * F_DIM * N_NODES + 255) / 256), dim3(256), 0, stream, x, out);
}

// Round 5
// 539.628 us; speedup vs baseline: 2.7823x; 1.0368x over previous
//
#include <hip/hip_runtime.h>
#include <math.h>

// Problem constants
#define F_DIM 64
#define N_NODES 64
#define T_LEN 24
#define N_HEADS 8
#define BATCH 16
#define E_DIM 4096          // F_DIM * N_NODES
#define HD 512              // E / N_HEADS
#define QKV_N 12288         // 3*E
#define MB 384              // T_LEN * BATCH
#define TS 23               // T_LEN - 1
#define MP 368              // TS * BATCH
#define MPAD 384            // padded row count for both GEMMs

typedef unsigned short ushort_t;
typedef short bf16x8 __attribute__((ext_vector_type(8)));
typedef float f32x4 __attribute__((ext_vector_type(4)));

// fp32 -> bf16, round-half-up (add 0x8000, truncate)
__device__ inline ushort_t f2bf(float f) {
    return (ushort_t)((__float_as_uint(f) + 0x8000u) >> 16);
}

// async global->LDS, 16B per lane. LDS dest = uniform base + lane*16.
__device__ inline void async_load16(const ushort_t* g, ushort_t* lds) {
    __builtin_amdgcn_global_load_lds(
        (const __attribute__((address_space(1))) unsigned int*)g,
        (__attribute__((address_space(3))) unsigned int*)lds,
        16, 0, 0);
}

// ---------------------------------------------------------------------------
// Kernel 0: xt[t*16+b, f*64+n] = bf16(x[b, f, t, n])
// ---------------------------------------------------------------------------
__global__ void k_transpose(const float* __restrict__ x, ushort_t* __restrict__ xt) {
    int m = blockIdx.x;              // t*16 + b
    int t = m >> 4, b = m & 15;
    const float* xb = x + (size_t)b * (F_DIM * T_LEN * N_NODES) + (size_t)t * N_NODES;
    ushort_t* row = xt + (size_t)m * E_DIM;
    for (int e = threadIdx.x; e < E_DIM; e += 256) {
        int f = e >> 6, n = e & 63;
        row[e] = f2bf(xb[(size_t)f * (T_LEN * N_NODES) + n]);
    }
}

// ---------------------------------------------------------------------------
// MFMA GEMM, M-full tiling: block tile = 384 (all M) x 64 (N), BK=32.
// Every weight byte loaded exactly once (no m-tile B re-reads). 4 waves, each
// owns 96 rows x 64 cols = 6x4 16x16x32 frags (96 accum VGPRs/lane).
// A: bf16 in ws (384 rows). B: fp32 weights -> bf16 via v_perm during staging.
// blockIdx.z = K-chunk of kc cols; raw partials, bias added in k_reduce.
// ---------------------------------------------------------------------------
__global__ __launch_bounds__(256) void k_gemm_mfma(
    const ushort_t* __restrict__ A, const float* __restrict__ B,
    float* __restrict__ P, int N, int K, int kc)
{
    __shared__ __align__(16) ushort_t As[384 * 32];   // 24 KB
    __shared__ __align__(16) ushort_t Bs[64 * 32];    // 4 KB
    const int tid  = threadIdx.x;
    const int wave = tid >> 6, lane = tid & 63;
    const int lr = lane & 15, lq = lane >> 4;
    const int n0 = blockIdx.x * 64;
    const int kz = blockIdx.z * kc;

    f32x4 acc[6][4];
    #pragma unroll
    for (int i = 0; i < 6; ++i)
        #pragma unroll
        for (int j = 0; j < 4; ++j)
            acc[i][j] = (f32x4){0.f, 0.f, 0.f, 0.f};

    // A staging: 384x32 bf16 = 24 KB = 24 wave-instructions; 6 per wave.
    // Instruction (w,s) covers rows (w*6+s)*16 + (lane>>2), k-part (lane&3)*8.
    const int rb = lane >> 2, kp = (lane & 3) * 8;
    const ushort_t* gA[6];
    ushort_t* lA[6];
    #pragma unroll
    for (int s = 0; s < 6; ++s) {
        int r = (wave * 6 + s) * 16 + rb;
        gA[s] = A + (size_t)r * K + kp;
        lA[s] = As + (wave * 6 + s) * 512;   // 512 ushorts = 1024 B per instr
    }

    for (int k0 = kz; k0 < kz + kc; k0 += 32) {
        #pragma unroll
        for (int s = 0; s < 6; ++s) async_load16(gA[s] + k0, lA[s]);
        // B: 64x32 fp32 = 512 float4; 2 per thread, convert via v_perm
        #pragma unroll
        for (int s = 0; s < 2; ++s) {
            int e4  = tid + s * 256;
            int row = e4 >> 3;
            int kq  = (e4 & 7) * 4;
            const float4 v = *(const float4*)(B + (size_t)(n0 + row) * K + k0 + kq);
            unsigned int ux = __float_as_uint(v.x) + 0x8000u;
            unsigned int uy = __float_as_uint(v.y) + 0x8000u;
            unsigned int uz = __float_as_uint(v.z) + 0x8000u;
            unsigned int uw = __float_as_uint(v.w) + 0x8000u;
            unsigned int p0 = __builtin_amdgcn_perm(uy, ux, 0x07060302u);
            unsigned int p1 = __builtin_amdgcn_perm(uw, uz, 0x07060302u);
            *(uint2*)&Bs[row * 32 + kq] = make_uint2(p0, p1);
        }
        __syncthreads();
        bf16x8 af[6], bfr[4];
        #pragma unroll
        for (int i = 0; i < 6; ++i)
            af[i] = *(const bf16x8*)&As[(wave * 96 + i * 16 + lr) * 32 + lq * 8];
        #pragma unroll
        for (int j = 0; j < 4; ++j)
            bfr[j] = *(const bf16x8*)&Bs[(j * 16 + lr) * 32 + lq * 8];
        #pragma unroll
        for (int i = 0; i < 6; ++i)
            #pragma unroll
            for (int j = 0; j < 4; ++j)
                acc[i][j] = __builtin_amdgcn_mfma_f32_16x16x32_bf16(af[i], bfr[j], acc[i][j], 0, 0, 0);
        __syncthreads();
    }

    // epilogue: raw partial store (all 384 rows valid; no guards)
    float* Pz = P + (size_t)blockIdx.z * MPAD * N;
    #pragma unroll
    for (int i = 0; i < 6; ++i) {
        int m = wave * 96 + i * 16 + lq * 4;
        #pragma unroll
        for (int r = 0; r < 4; ++r) {
            #pragma unroll
            for (int j = 0; j < 4; ++j)
                Pz[(size_t)(m + r) * N + n0 + j * 16 + lr] = acc[i][j][r];
        }
    }
}

// ---------------------------------------------------------------------------
// k_reduce: C[m,n] = sum_s P[s,m,n] + bias[n]   (float4-vectorized)
// ---------------------------------------------------------------------------
__global__ void k_reduce(const float* __restrict__ P, const float* __restrict__ bias,
                         float* __restrict__ C, int N, int S) {
    int idx = blockIdx.x * 256 + threadIdx.x;      // float4 index; grid exact
    size_t e = (size_t)idx * 4;
    int n = (int)(e % N);
    float4 a = *(const float4*)(P + e);
    for (int s = 1; s < S; ++s) {
        const float4 b = *(const float4*)(P + (size_t)s * MPAD * N + e);
        a.x += b.x; a.y += b.y; a.z += b.z; a.w += b.w;
    }
    const float4 bb = *(const float4*)(bias + n);
    a.x += bb.x; a.y += bb.y; a.z += bb.z; a.w += bb.w;
    *(float4*)(C + e) = a;
}

// ---------------------------------------------------------------------------
// k_attn (fused scores + cbar): per (b,h):
//   scores -> prefix softmax -> wbar[t,k] = (1/(t+1)) sum_{q<=t} E[q,k]/S[q,t]
//   cbar[t*16+b, h*512+d] = bf16( sum_k wbar[t,k] * v[k,b,h,d] )
// ---------------------------------------------------------------------------
__global__ __launch_bounds__(512) void k_attn(const float* __restrict__ qkv,
                                              ushort_t* __restrict__ cbar) {
    int bh = blockIdx.x;             // b*8 + h
    int b = bh >> 3, h = bh & 7;
    __shared__ float vs[T_LEN * HD];     // 48 KB
    __shared__ float ss[T_LEN][25];
    __shared__ float isv[T_LEN][25];
    __shared__ float wbs[TS * T_LEN];
    int tid = threadIdx.x, wave = tid >> 6, lane = tid & 63;
    // V -> LDS (overlaps with score dots below)
    for (int i4 = tid; i4 < T_LEN * HD / 4; i4 += 512) {
        int t = i4 >> 7, d4 = (i4 & 127) * 4;
        *(float4*)&vs[t * HD + d4] =
            *(const float4*)&qkv[(size_t)(t * BATCH + b) * QKV_N + 2 * E_DIM + h * HD + d4];
    }
    const float scale = 0.044194173824159216f;   // 1/sqrt(512)
    for (int p = wave; p < T_LEN * T_LEN; p += 8) {   // wave-per-dot, coalesced
        int qi = p / 24, ki = p - qi * 24;
        const float* qp = qkv + (size_t)(qi * BATCH + b) * QKV_N + h * HD + lane * 8;
        const float* kp = qkv + (size_t)(ki * BATCH + b) * QKV_N + E_DIM + h * HD + lane * 8;
        float4 a0 = *(const float4*)qp, a1 = *(const float4*)(qp + 4);
        float4 c0 = *(const float4*)kp, c1 = *(const float4*)(kp + 4);
        float s = a0.x * c0.x + a0.y * c0.y + a0.z * c0.z + a0.w * c0.w
                + a1.x * c1.x + a1.y * c1.y + a1.z * c1.z + a1.w * c1.w;
        #pragma unroll
        for (int off = 32; off > 0; off >>= 1) s += __shfl_xor(s, off);
        if (lane == 0) {
            s *= scale;
            if (ki <= qi) s += 1.f;      // tril_add (includes diagonal)
            ss[qi][ki] = s;
        }
    }
    __syncthreads();
    if (tid < T_LEN) {
        int q = tid;
        float M = -1e30f;
        for (int k = 0; k < T_LEN; ++k) M = fmaxf(M, ss[q][k]);
        float run = 0.f;
        for (int k = 0; k < T_LEN; ++k) {
            float e = __expf(ss[q][k] - M);
            ss[q][k] = e;
            run += e;
            isv[q][k] = 1.f / run;   // 1 / S[q, t=k]
        }
    }
    __syncthreads();
    for (int p = tid; p < TS * T_LEN; p += 512) {
        int t = p / 24, k = p - t * 24;
        float w = 0.f;
        if (k <= t) {
            float sum = 0.f;
            for (int q = 0; q <= t; ++q) sum += ss[q][k] * isv[q][t];
            w = sum / (float)(t + 1);
        }
        wbs[p] = w;
    }
    __syncthreads();
    int d = tid;                        // 512 threads == HD
    for (int t = 0; t < TS; ++t) {
        float a = 0.f;
        #pragma unroll
        for (int k = 0; k < T_LEN; ++k) a += wbs[t * 24 + k] * vs[k * HD + d];
        cbar[(size_t)(t * BATCH + b) * E_DIM + h * HD + d] = f2bf(a);
    }
}

// ---------------------------------------------------------------------------
// k_final: out[b, f, t+1, n] = relu( sum_g pooled[t*16+b, f*64+g]*Wfc[n,g] + bfc[n] )
// ---------------------------------------------------------------------------
__global__ void k_final(const float* __restrict__ pooled, const float* __restrict__ Wfc,
                        const float* __restrict__ bfc, float* __restrict__ out) {
    int tb = blockIdx.x;             // t*16 + b
    int t = tb >> 4, b = tb & 15;
    __shared__ float ps[E_DIM];      // 16 KB
    __shared__ float wf[64 * 65];    // padded
    __shared__ float bf[64];
    int tid = threadIdx.x;
    for (int i = tid; i < E_DIM; i += 256) ps[i] = pooled[(size_t)tb * E_DIM + i];
    for (int i = tid; i < 64 * 64; i += 256) wf[(i >> 6) * 65 + (i & 63)] = Wfc[i];
    if (tid < 64) bf[tid] = bfc[tid];
    __syncthreads();
    for (int p = tid; p < 4096; p += 256) {
        int f = p >> 6, n = p & 63;
        float acc = bf[n];
        #pragma unroll
        for (int g = 0; g < 64; ++g) acc += ps[f * 64 + g] * wf[n * 65 + g];
        out[(size_t)((b * 64 + f) * T_LEN + (t + 1)) * N_NODES + n] = fmaxf(acc, 0.f);
    }
}

// k_first: out[b,f,0,n] = x[b,f,0,n]   (65536 elems, 256 blocks)
__global__ void k_first(const float* __restrict__ x, float* __restrict__ out) {
    int idx = blockIdx.x * 256 + threadIdx.x;
    if (idx >= BATCH * F_DIM * N_NODES) return;
    int b = idx >> 12, f = (idx >> 6) & 63, n = idx & 63;
    size_t o = ((size_t)(b * 64 + f) * T_LEN) * 64 + n;
    out[o] = x[o];
}

extern "C" void kernel_launch(void* const* d_in, const int* in_sizes, int n_in,
                              void* d_out, int out_size, void* d_ws, size_t ws_size,
                              hipStream_t stream) {
    const float* x    = (const float*)d_in[0];
    const float* Wqkv = (const float*)d_in[1];
    const float* bqkv = (const float*)d_in[2];
    const float* Wo   = (const float*)d_in[3];
    const float* bo   = (const float*)d_in[4];
    const float* Wfc  = (const float*)d_in[5];
    const float* bfc  = (const float*)d_in[6];
    float* out = (float*)d_out;

    // ws layout (bytes): xt bf16 | qkv f32 | cbar bf16 | pooled f32 | pbuf f32
    char* wsb = (char*)d_ws;
    ushort_t* xt   = (ushort_t*)wsb;                                  //  3,145,728
    float*    qkv  = (float*)(wsb + 3145728);                         // 18,874,368
    ushort_t* cbar = (ushort_t*)(wsb + 3145728 + 18874368);           //  3,145,728
    float*  pooled = (float*)(wsb + 3145728 + 18874368 + 3145728);    //  6,291,456
    size_t base    = 3145728 + 18874368 + 3145728 + 6291456;
    float*  pbuf   = (float*)(wsb + base);

    const size_t pq = (size_t)MPAD * QKV_N * 4;    // QKV partial: 18.87 MB
    const size_t po = (size_t)MPAD * E_DIM * 4;    // Wo partial:   6.29 MB
    int S = (ws_size >= base + 2 * pq) ? 2 : 1;                  // QKV K-split
    int Swo = (ws_size >= base + 8 * po) ? 8 : ((ws_size >= base + 4 * po) ? 4 : 1);

    hipLaunchKernelGGL(k_transpose, dim3(MB), dim3(256), 0, stream, x, xt);

    hipLaunchKernelGGL(k_gemm_mfma, dim3(QKV_N / 64, 1, S), dim3(256), 0, stream,
                       xt, Wqkv, pbuf, QKV_N, E_DIM, E_DIM / S);
    hipLaunchKernelGGL(k_reduce, dim3(MPAD * QKV_N / 4 / 256), dim3(256), 0, stream,
                       pbuf, bqkv, qkv, QKV_N, S);

    hipLaunchKernelGGL(k_attn, dim3(BATCH * N_HEADS), dim3(512), 0, stream, qkv, cbar);

    hipLaunchKernelGGL(k_gemm_mfma, dim3(E_DIM / 64, 1, Swo), dim3(256), 0, stream,
                       cbar, Wo, pbuf, E_DIM, E_DIM, E_DIM / Swo);
    hipLaunchKernelGGL(k_reduce, dim3(MPAD * E_DIM / 4 / 256), dim3(256), 0, stream,
                       pbuf, bo, pooled, E_DIM, Swo);

    hipLaunchKernelGGL(k_final, dim3(TS * BATCH), dim3(256), 0, stream, pooled, Wfc, bfc, out);
    hipLaunchKernelGGL(k_first, dim3((BATCH * F_DIM * N_NODES + 255) / 256), dim3(256), 0, stream, x, out);
}